// Round 8
// baseline (15191.061 us; speedup 1.0000x reference)
//
#include <hip/hip_runtime.h>
#include <math.h>

// Problem constants (reference: B,T,D,H = 32,2048,512,512)
#define BB   32
#define TT   2048
#define DD   512
#define HH   512
#define G4H  2048   // 4*H

// ---------------------------------------------------------------------------
// Phase A: xw[t_local*32 + b][col] = sum_d X[b][t0+t][d] * W[d][col] + bias[col]
// fp32 tiled GEMM: 128x128 block tile, 16 K-step, 256 threads, 8x8 microtile.
// Also zeroes the 8 group barrier counters on the first chunk (t0==0).
// ---------------------------------------------------------------------------
__global__ __launch_bounds__(256, 2) void gemm_xw(
    const float* __restrict__ X, const float* __restrict__ Wm,
    const float* __restrict__ bias, float* __restrict__ xw,
    int t0, unsigned int* __restrict__ ctr)
{
    if (t0 == 0 && blockIdx.x == 0 && blockIdx.y == 0 && threadIdx.x < 8)
        ctr[threadIdx.x * 64] = 0u;

    __shared__ float As[16][128];
    __shared__ float Bs[16][128];

    const int tid  = threadIdx.x;
    const int row0 = blockIdx.y * 128;   // rows: (t_local, b) t-major
    const int col0 = blockIdx.x * 128;
    const int tx = tid & 15;
    const int ty = tid >> 4;

    float acc[8][8];
    #pragma unroll
    for (int i = 0; i < 8; ++i)
        #pragma unroll
        for (int j = 0; j < 8; ++j) acc[i][j] = 0.f;

    for (int k0 = 0; k0 < DD; k0 += 16) {
        #pragma unroll
        for (int i = 0; i < 2; ++i) {
            int qa = tid + i * 256;          // 0..511 quads
            int r  = qa >> 2, kq = qa & 3;
            int grow = row0 + r;
            int b = grow & 31, tl = grow >> 5;
            const float4 a = *(const float4*)(X + ((size_t)b * TT + t0 + tl) * DD + k0 + kq * 4);
            As[kq*4+0][r] = a.x; As[kq*4+1][r] = a.y;
            As[kq*4+2][r] = a.z; As[kq*4+3][r] = a.w;

            int qb = tid + i * 256;
            int kb = qb >> 5, c4 = qb & 31;
            *(float4*)&Bs[kb][c4*4] =
                *(const float4*)(Wm + (size_t)(k0 + kb) * G4H + col0 + c4 * 4);
        }
        __syncthreads();

        #pragma unroll
        for (int k = 0; k < 16; ++k) {
            float a[8], b[8];
            #pragma unroll
            for (int i = 0; i < 8; ++i) a[i] = As[k][ty*8 + i];
            #pragma unroll
            for (int j = 0; j < 8; ++j) b[j] = Bs[k][tx*8 + j];
            #pragma unroll
            for (int i = 0; i < 8; ++i)
                #pragma unroll
                for (int j = 0; j < 8; ++j) acc[i][j] += a[i] * b[j];
        }
        __syncthreads();
    }

    #pragma unroll
    for (int i = 0; i < 8; ++i) {
        int grow = row0 + ty*8 + i;
        float* dst = xw + (size_t)grow * G4H + col0 + tx*8;
        #pragma unroll
        for (int j = 0; j < 8; j += 4) {
            float4 v;
            v.x = acc[i][j+0] + bias[col0 + tx*8 + j + 0];
            v.y = acc[i][j+1] + bias[col0 + tx*8 + j + 1];
            v.z = acc[i][j+2] + bias[col0 + tx*8 + j + 2];
            v.w = acc[i][j+3] + bias[col0 + tx*8 + j + 3];
            *(float4*)(dst + j) = v;
        }
    }
}

// ---------------------------------------------------------------------------
// Phase B: persistent recurrent kernel, LDS-resident weights.
// Grid = 256 blocks x 256 threads. p = blockIdx%8 (batches 4p..4p+3),
// q = blockIdx/8 (hidden units 16q..16q+15 -> 64 gate columns, col=lane).
// Wave w (0..3) = K-slice of 128 (compute) = batch (reduce/update).
//
// Sync rebuild this round: WAVE-granular rendezvous, zero __syncthreads on
// the sync path.
//  - Arrival: each wave drains its own h stores (s_waitcnt vmcnt(0)) then
//    lane0 does one relaxed system fetch_add. 128 arrivals/step.
//  - Spin: every wave spins on the counter (uniform addr = 1 req/poll) and
//    exits independently, immediately issuing its h loads.
//  - h staging is wave-local (each wave ds_writes/reads only its own
//    k-slice region of hbuf) -> ordered by lgkmcnt(0)+sched_barrier(0),
//    no block barrier (rule #18).
//  - One __syncthreads/step remains: the cross-wave red[] reduce. Cross-
//    step WAR on red[] is ordered by the rendezvous itself (writes at t+1
//    occur after spin-exit(t), which requires all reads(t) completed).
// All cross-block data stays relaxed system-scope at L3 (R6 protocol).
// ---------------------------------------------------------------------------
__global__ __launch_bounds__(256, 1) void lstm_rec(
    const float* __restrict__ W,
    const float* __restrict__ h_init,
    const float* __restrict__ xw,
    float* out,
    float* __restrict__ c_ws,
    unsigned int* ctr,
    int t0, int nT)
{
    __shared__ float4 wlds[128][64];    // [k>>2][col_local] = w[4k..4k+3][col]
    __shared__ float  hbuf[4][HH];      // h staging; region [b][w*128..] is wave-local
    __shared__ float  red[4][4][64];    // [kslice-wave][batch][lane]

    const int tid  = threadIdx.x;
    const int p    = blockIdx.x & 7;
    const int q    = blockIdx.x >> 3;
    const int w    = tid >> 6;          // wave id = K-slice (compute) = batch (reduce)
    const int lane = tid & 63;
    const int gi   = lane >> 4;
    const int u    = lane & 15;
    const int col  = gi * HH + q * 16 + u;   // this lane's global gate column

    // One-time: stage this block's recurrent W slice into LDS, k-packed.
    {
        const int cc = tid & 63;
        const int kq = tid >> 6;
        const int cg = (cc >> 4) * HH + q * 16 + (cc & 15);  // global col of cc
        const float* Wr = W + (size_t)DD * G4H + cg;
        #pragma unroll 4
        for (int i = 0; i < 32; ++i) {
            const int k4 = i * 4 + kq;          // 0..127
            float4 v;
            v.x = Wr[(size_t)(4 * k4 + 0) * G4H];
            v.y = Wr[(size_t)(4 * k4 + 1) * G4H];
            v.z = Wr[(size_t)(4 * k4 + 2) * G4H];
            v.w = Wr[(size_t)(4 * k4 + 3) * G4H];
            wlds[k4][cc] = v;
        }
    }
    __syncthreads();

    // c state: lanes 0..15 of wave w hold c[batch 4p+w][unit q*16+lane]
    float c = 0.f;
    if (t0 > 0 && lane < 16)
        c = c_ws[(size_t)(4 * p + w) * HH + q * 16 + lane];

    unsigned int* myctr = ctr + p * 64;
    const int k4b  = w * 32;              // this wave's k-slice, in float4 units
    const int hoff = w * 128 + lane * 2;  // this lane's h elements (k-slice)

    // Prologue: load xw for step 0.
    float xg = xw[((size_t)0 * BB + 4 * p + w) * G4H + col];

    for (int t = 0; t < nT; ++t) {
        const int gt = t0 + t;

        // 1) h ingest first (critical path): this wave's k-slice, 4 batches,
        //    2 floats/lane, relaxed system-scope (fresh L3, no cache ops).
        float2 hr0, hr1, hr2, hr3;
        if (gt == 0) {
            const float2 hv = *(const float2*)(h_init + hoff);
            hr0 = hv; hr1 = hv; hr2 = hv; hr3 = hv;
        } else {
            const float* o0 = &out[((size_t)(4 * p + 0) * TT + (gt - 1)) * HH + hoff];
            const float* o1 = &out[((size_t)(4 * p + 1) * TT + (gt - 1)) * HH + hoff];
            const float* o2 = &out[((size_t)(4 * p + 2) * TT + (gt - 1)) * HH + hoff];
            const float* o3 = &out[((size_t)(4 * p + 3) * TT + (gt - 1)) * HH + hoff];
            hr0.x = __hip_atomic_load(o0 + 0, __ATOMIC_RELAXED, __HIP_MEMORY_SCOPE_SYSTEM);
            hr0.y = __hip_atomic_load(o0 + 1, __ATOMIC_RELAXED, __HIP_MEMORY_SCOPE_SYSTEM);
            hr1.x = __hip_atomic_load(o1 + 0, __ATOMIC_RELAXED, __HIP_MEMORY_SCOPE_SYSTEM);
            hr1.y = __hip_atomic_load(o1 + 1, __ATOMIC_RELAXED, __HIP_MEMORY_SCOPE_SYSTEM);
            hr2.x = __hip_atomic_load(o2 + 0, __ATOMIC_RELAXED, __HIP_MEMORY_SCOPE_SYSTEM);
            hr2.y = __hip_atomic_load(o2 + 1, __ATOMIC_RELAXED, __HIP_MEMORY_SCOPE_SYSTEM);
            hr3.x = __hip_atomic_load(o3 + 0, __ATOMIC_RELAXED, __HIP_MEMORY_SCOPE_SYSTEM);
            hr3.y = __hip_atomic_load(o3 + 1, __ATOMIC_RELAXED, __HIP_MEMORY_SCOPE_SYSTEM);
        }

        // 2) Prefetch next step's x-part (a full step of latency cover).
        float xg_next = 0.f;
        if (t + 1 < nT)
            xg_next = xw[((size_t)(t + 1) * BB + 4 * p + w) * G4H + col];

        // 3) Wave-local stage to LDS (only wave w touches region [*][w*128..]).
        *(float2*)&hbuf[0][hoff] = hr0;
        *(float2*)&hbuf[1][hoff] = hr1;
        *(float2*)&hbuf[2][hoff] = hr2;
        *(float2*)&hbuf[3][hoff] = hr3;
        asm volatile("s_waitcnt lgkmcnt(0)" ::: "memory");
        __builtin_amdgcn_sched_barrier(0);

        // 4) K-slice dot: per-lane wlds b128 + same-address broadcast hbuf
        //    reads (no conflict, cheap) + 512 FMA.
        const float4* hb0 = (const float4*)&hbuf[0][w * 128];
        const float4* hb1 = (const float4*)&hbuf[1][w * 128];
        const float4* hb2 = (const float4*)&hbuf[2][w * 128];
        const float4* hb3 = (const float4*)&hbuf[3][w * 128];

        float a0 = 0.f, a1 = 0.f, a2 = 0.f, a3 = 0.f;
        #pragma unroll
        for (int j = 0; j < 32; ++j) {
            const float4 wv = wlds[k4b + j][lane];
            const float4 h0 = hb0[j];
            const float4 h1 = hb1[j];
            const float4 h2 = hb2[j];
            const float4 h3 = hb3[j];
            a0 += wv.x*h0.x; a0 += wv.y*h0.y; a0 += wv.z*h0.z; a0 += wv.w*h0.w;
            a1 += wv.x*h1.x; a1 += wv.y*h1.y; a1 += wv.z*h1.z; a1 += wv.w*h1.w;
            a2 += wv.x*h2.x; a2 += wv.y*h2.y; a2 += wv.z*h2.z; a2 += wv.w*h2.w;
            a3 += wv.x*h3.x; a3 += wv.y*h3.y; a3 += wv.z*h3.z; a3 += wv.w*h3.w;
        }

        red[w][0][lane] = a0; red[w][1][lane] = a1;
        red[w][2][lane] = a2; red[w][3][lane] = a3;
        __syncthreads();                         // the ONE block barrier/step

        // 5) Wave w reduces batch w, adds x-part (+bias), updates, stores h.
        float g = red[0][w][lane] + red[1][w][lane]
                + red[2][w][lane] + red[3][w][lane] + xg;

        const int ul = lane & 15;
        const float fv = __shfl(g, ul);
        const float iv = __shfl(g, ul + 16);
        const float ov = __shfl(g, ul + 32);
        const float gv = __shfl(g, ul + 48);
        if (lane < 16) {
            const float sf = 1.f / (1.f + __expf(-fv));
            const float si = 1.f / (1.f + __expf(-iv));
            const float so = 1.f / (1.f + __expf(-ov));
            const float tg = 1.f - 2.f / (__expf(2.f * gv) + 1.f);
            c = sf * c + si * tg;
            const float tc = 1.f - 2.f / (__expf(2.f * c) + 1.f);
            const float h = so * tc;
            __hip_atomic_store(
                &out[((size_t)(4 * p + w) * TT + gt) * HH + q * 16 + lane],
                h, __ATOMIC_RELAXED, __HIP_MEMORY_SCOPE_SYSTEM);
        }

        // 6) Wave-granular rendezvous: drain own stores, arrive, spin.
        asm volatile("s_waitcnt vmcnt(0)" ::: "memory");
        if (lane == 0)
            __hip_atomic_fetch_add(myctr, 1u, __ATOMIC_RELAXED, __HIP_MEMORY_SCOPE_SYSTEM);
        const unsigned int tgt = 128u * (unsigned int)(gt + 1);
        while (__hip_atomic_load(myctr, __ATOMIC_RELAXED, __HIP_MEMORY_SCOPE_SYSTEM) < tgt) {}
        asm volatile("" ::: "memory");

        xg = xg_next;
    }

    // Spill c state for the next chunk (kernel boundary = coherence).
    if (lane < 16)
        c_ws[(size_t)(4 * p + w) * HH + q * 16 + lane] = c;
}

// ---------------------------------------------------------------------------
extern "C" void kernel_launch(void* const* d_in, const int* in_sizes, int n_in,
                              void* d_out, int out_size, void* d_ws, size_t ws_size,
                              hipStream_t stream) {
    const float* x      = (const float*)d_in[0];
    // d_in[1] = input_paddings (unused)
    const float* W      = (const float*)d_in[2];
    const float* bias   = (const float*)d_in[3];
    const float* h_init = (const float*)d_in[4];
    float* out = (float*)d_out;

    // Pick the largest chunk of T whose xw buffer fits in ws
    // (xw chunk = CT*32*2048*4 bytes; + 2KB counters + 64KB c-state).
    static const int cand[] = {2048, 1024, 512, 256, 128, 64, 32, 16, 8, 4};
    int CT = 4;
    for (int i = 0; i < 10; ++i) {
        if ((size_t)cand[i] * BB * G4H * 4 + 2048 + 65536 <= ws_size) { CT = cand[i]; break; }
    }
    const size_t xw_bytes = (size_t)CT * BB * G4H * 4;
    float*        xw   = (float*)d_ws;
    unsigned int* ctr  = (unsigned int*)((char*)d_ws + xw_bytes);
    float*        c_ws = (float*)((char*)d_ws + xw_bytes + 2048);

    for (int t0 = 0; t0 < TT; t0 += CT) {
        dim3 g(G4H / 128, CT * BB / 128);
        gemm_xw<<<g, 256, 0, stream>>>(x, W, bias, xw, t0, ctr);
        lstm_rec<<<256, 256, 0, stream>>>(W, h_init, xw, out, c_ws, ctr, t0, CT);
    }
}

// Round 10
// 12134.377 us; speedup vs baseline: 1.2519x; 1.2519x over previous
//
#include <hip/hip_runtime.h>
#include <math.h>

// Problem constants (reference: B,T,D,H = 32,2048,512,512)
#define BB   32
#define TT   2048
#define DD   512
#define HH   512
#define G4H  2048   // 4*H

// ---------------------------------------------------------------------------
// Phase A: xw[t_local*32 + b][col] = sum_d X[b][t0+t][d] * W[d][col] + bias[col]
// fp32 tiled GEMM: 128x128 block tile, 16 K-step, 256 threads, 8x8 microtile.
// At t0==0 also zeroes the 8 group counters and the hx tag-exchange buffer
// (tags stored are >=1, so zeroed/poisoned/leftover words can never be
// accepted by a consumer before the real producer writes them).
// ---------------------------------------------------------------------------
__global__ __launch_bounds__(256, 2) void gemm_xw(
    const float* __restrict__ X, const float* __restrict__ Wm,
    const float* __restrict__ bias, float* __restrict__ xw,
    int t0, unsigned int* __restrict__ ctr, unsigned long long* __restrict__ hx)
{
    if (t0 == 0) {
        if (blockIdx.x == 0 && blockIdx.y == 0 && threadIdx.x < 8)
            ctr[threadIdx.x * 64] = 0u;
        if (blockIdx.x == 0) {
            const int n = 2 * BB * HH;               // 32768 u64 slots
            const int stride = gridDim.y * 256;
            for (int i = blockIdx.y * 256 + threadIdx.x; i < n; i += stride)
                hx[i] = 0ull;
        }
    }

    __shared__ float As[16][128];
    __shared__ float Bs[16][128];

    const int tid  = threadIdx.x;
    const int row0 = blockIdx.y * 128;   // rows: (t_local, b) t-major
    const int col0 = blockIdx.x * 128;
    const int tx = tid & 15;
    const int ty = tid >> 4;

    float acc[8][8];
    #pragma unroll
    for (int i = 0; i < 8; ++i)
        #pragma unroll
        for (int j = 0; j < 8; ++j) acc[i][j] = 0.f;

    for (int k0 = 0; k0 < DD; k0 += 16) {
        #pragma unroll
        for (int i = 0; i < 2; ++i) {
            int qa = tid + i * 256;          // 0..511 quads
            int r  = qa >> 2, kq = qa & 3;
            int grow = row0 + r;
            int b = grow & 31, tl = grow >> 5;
            const float4 a = *(const float4*)(X + ((size_t)b * TT + t0 + tl) * DD + k0 + kq * 4);
            As[kq*4+0][r] = a.x; As[kq*4+1][r] = a.y;
            As[kq*4+2][r] = a.z; As[kq*4+3][r] = a.w;

            int qb = tid + i * 256;
            int kb = qb >> 5, c4 = qb & 31;
            *(float4*)&Bs[kb][c4*4] =
                *(const float4*)(Wm + (size_t)(k0 + kb) * G4H + col0 + c4 * 4);
        }
        __syncthreads();

        #pragma unroll
        for (int k = 0; k < 16; ++k) {
            float a[8], b[8];
            #pragma unroll
            for (int i = 0; i < 8; ++i) a[i] = As[k][ty*8 + i];
            #pragma unroll
            for (int j = 0; j < 8; ++j) b[j] = Bs[k][tx*8 + j];
            #pragma unroll
            for (int i = 0; i < 8; ++i)
                #pragma unroll
                for (int j = 0; j < 8; ++j) acc[i][j] += a[i] * b[j];
        }
        __syncthreads();
    }

    #pragma unroll
    for (int i = 0; i < 8; ++i) {
        int grow = row0 + ty*8 + i;
        float* dst = xw + (size_t)grow * G4H + col0 + tx*8;
        #pragma unroll
        for (int j = 0; j < 8; j += 4) {
            float4 v;
            v.x = acc[i][j+0] + bias[col0 + tx*8 + j + 0];
            v.y = acc[i][j+1] + bias[col0 + tx*8 + j + 1];
            v.z = acc[i][j+2] + bias[col0 + tx*8 + j + 2];
            v.w = acc[i][j+3] + bias[col0 + tx*8 + j + 3];
            *(float4*)(dst + j) = v;
        }
    }
}

// ---------------------------------------------------------------------------
// Phase B: persistent recurrent kernel, LDS-resident weights, TAGGED-DATAFLOW
// h exchange (no produce->consume barrier on the critical path).
//
// Grid = 256 blocks x 256 threads. p = blockIdx%8 (batches 4p..4p+3),
// q = blockIdx/8 (units 16q..16q+15 -> 64 gate columns, col=lane).
// Wave w (0..3) = K-slice of 128 (compute) = batch (reduce/update).
//
// h element = one 8B word in hx[2][32][512]: {hi32 = tag = step+1,
// lo32 = fp32 h bits}, written with a single relaxed system-scope 8B
// atomic store (value+tag indivisible). Consumers spin on the tags of
// exactly the 8 words/lane they need (only the 8 producer blocks of the
// wave's k-slice gate progress, not the whole group). Double-buffered by
// step parity; WAR protection: before overwriting slot[gt&1] (= h(gt-2)),
// wait group ctr >= 32*gt (all 32 blocks ended step gt-1, i.e. consumed
// h(gt-2)). That wait sits one full step of work after the producers'
// own arrivals -> normally zero cost, off the critical path. Arrival = 1
// fetch_add per block per step (tid0, after the red-reduce barrier).
// fp32 `out` store is not read in-kernel anymore -> off the sync path.
// red[] is parity-double-buffered (closes the R7/R8 cross-step WAR race).
// ---------------------------------------------------------------------------
__global__ __launch_bounds__(256, 1) void lstm_rec(
    const float* __restrict__ W,
    const float* __restrict__ h_init,
    const float* __restrict__ xw,
    float* __restrict__ out,
    float* __restrict__ c_ws,
    unsigned int* ctr,
    unsigned long long* hx,
    int t0, int nT)
{
    __shared__ float4 wlds[128][64];    // [k>>2][col_local] = w[4k..4k+3][col]
    __shared__ float  hbuf[4][HH];      // h staging; region [b][w*128..] is wave-local
    __shared__ float  red[2][4][4][64]; // [parity][kslice-wave][batch][lane]

    const int tid  = threadIdx.x;
    const int p    = blockIdx.x & 7;
    const int q    = blockIdx.x >> 3;
    const int w    = tid >> 6;          // wave id = K-slice (compute) = batch (reduce)
    const int lane = tid & 63;
    const int gi   = lane >> 4;
    const int u    = lane & 15;
    const int col  = gi * HH + q * 16 + u;   // this lane's global gate column

    // One-time: stage this block's recurrent W slice into LDS, k-packed.
    {
        const int cc = tid & 63;
        const int kq = tid >> 6;
        const int cg = (cc >> 4) * HH + q * 16 + (cc & 15);  // global col of cc
        const float* Wr = W + (size_t)DD * G4H + cg;
        #pragma unroll 4
        for (int i = 0; i < 32; ++i) {
            const int k4 = i * 4 + kq;          // 0..127
            float4 v;
            v.x = Wr[(size_t)(4 * k4 + 0) * G4H];
            v.y = Wr[(size_t)(4 * k4 + 1) * G4H];
            v.z = Wr[(size_t)(4 * k4 + 2) * G4H];
            v.w = Wr[(size_t)(4 * k4 + 3) * G4H];
            wlds[k4][cc] = v;
        }
    }
    __syncthreads();

    // c state: lanes 0..15 of wave w hold c[batch 4p+w][unit q*16+lane]
    float c = 0.f;
    if (t0 > 0 && lane < 16)
        c = c_ws[(size_t)(4 * p + w) * HH + q * 16 + lane];

    unsigned int* myctr = ctr + p * 64;
    const int k4b  = w * 32;              // this wave's k-slice, in float4 units
    const int hoff = w * 128 + lane * 2;  // this lane's h elements (k-slice)

    // Prologue: load xw for step 0.
    float xg = xw[((size_t)0 * BB + 4 * p + w) * G4H + col];

    for (int t = 0; t < nT; ++t) {
        const int gt = t0 + t;

        // Prefetch next step's x-part (independent; issues first).
        float xg_next = 0.f;
        if (t + 1 < nT)
            xg_next = xw[((size_t)(t + 1) * BB + 4 * p + w) * G4H + col];

        // 1) h ingest via tagged dataflow: 8 words/lane (4 batches x 2 elems).
        float2 hr0, hr1, hr2, hr3;
        if (gt == 0) {
            const float2 hv = *(const float2*)(h_init + hoff);
            hr0 = hv; hr1 = hv; hr2 = hv; hr3 = hv;
        } else {
            const unsigned int want = (unsigned int)gt;   // tag of h(gt-1)
            const unsigned long long* hs = hx + (size_t)((gt - 1) & 1) * (BB * HH);
            const unsigned long long* a0 = hs + (size_t)(4 * p + 0) * HH + hoff;
            const unsigned long long* a1 = hs + (size_t)(4 * p + 1) * HH + hoff;
            const unsigned long long* a2 = hs + (size_t)(4 * p + 2) * HH + hoff;
            const unsigned long long* a3 = hs + (size_t)(4 * p + 3) * HH + hoff;
            unsigned long long v0 = __hip_atomic_load(a0 + 0, __ATOMIC_RELAXED, __HIP_MEMORY_SCOPE_SYSTEM);
            unsigned long long v1 = __hip_atomic_load(a0 + 1, __ATOMIC_RELAXED, __HIP_MEMORY_SCOPE_SYSTEM);
            unsigned long long v2 = __hip_atomic_load(a1 + 0, __ATOMIC_RELAXED, __HIP_MEMORY_SCOPE_SYSTEM);
            unsigned long long v3 = __hip_atomic_load(a1 + 1, __ATOMIC_RELAXED, __HIP_MEMORY_SCOPE_SYSTEM);
            unsigned long long v4 = __hip_atomic_load(a2 + 0, __ATOMIC_RELAXED, __HIP_MEMORY_SCOPE_SYSTEM);
            unsigned long long v5 = __hip_atomic_load(a2 + 1, __ATOMIC_RELAXED, __HIP_MEMORY_SCOPE_SYSTEM);
            unsigned long long v6 = __hip_atomic_load(a3 + 0, __ATOMIC_RELAXED, __HIP_MEMORY_SCOPE_SYSTEM);
            unsigned long long v7 = __hip_atomic_load(a3 + 1, __ATOMIC_RELAXED, __HIP_MEMORY_SCOPE_SYSTEM);
            for (;;) {
                bool bad = false;
                if ((unsigned int)(v0 >> 32) != want) { bad = true; v0 = __hip_atomic_load(a0 + 0, __ATOMIC_RELAXED, __HIP_MEMORY_SCOPE_SYSTEM); }
                if ((unsigned int)(v1 >> 32) != want) { bad = true; v1 = __hip_atomic_load(a0 + 1, __ATOMIC_RELAXED, __HIP_MEMORY_SCOPE_SYSTEM); }
                if ((unsigned int)(v2 >> 32) != want) { bad = true; v2 = __hip_atomic_load(a1 + 0, __ATOMIC_RELAXED, __HIP_MEMORY_SCOPE_SYSTEM); }
                if ((unsigned int)(v3 >> 32) != want) { bad = true; v3 = __hip_atomic_load(a1 + 1, __ATOMIC_RELAXED, __HIP_MEMORY_SCOPE_SYSTEM); }
                if ((unsigned int)(v4 >> 32) != want) { bad = true; v4 = __hip_atomic_load(a2 + 0, __ATOMIC_RELAXED, __HIP_MEMORY_SCOPE_SYSTEM); }
                if ((unsigned int)(v5 >> 32) != want) { bad = true; v5 = __hip_atomic_load(a2 + 1, __ATOMIC_RELAXED, __HIP_MEMORY_SCOPE_SYSTEM); }
                if ((unsigned int)(v6 >> 32) != want) { bad = true; v6 = __hip_atomic_load(a3 + 0, __ATOMIC_RELAXED, __HIP_MEMORY_SCOPE_SYSTEM); }
                if ((unsigned int)(v7 >> 32) != want) { bad = true; v7 = __hip_atomic_load(a3 + 1, __ATOMIC_RELAXED, __HIP_MEMORY_SCOPE_SYSTEM); }
                if (!bad) break;
            }
            hr0.x = __uint_as_float((unsigned int)v0);
            hr0.y = __uint_as_float((unsigned int)v1);
            hr1.x = __uint_as_float((unsigned int)v2);
            hr1.y = __uint_as_float((unsigned int)v3);
            hr2.x = __uint_as_float((unsigned int)v4);
            hr2.y = __uint_as_float((unsigned int)v5);
            hr3.x = __uint_as_float((unsigned int)v6);
            hr3.y = __uint_as_float((unsigned int)v7);
        }

        // 2) Wave-local stage to LDS (only wave w touches region [*][w*128..]).
        *(float2*)&hbuf[0][hoff] = hr0;
        *(float2*)&hbuf[1][hoff] = hr1;
        *(float2*)&hbuf[2][hoff] = hr2;
        *(float2*)&hbuf[3][hoff] = hr3;
        asm volatile("s_waitcnt lgkmcnt(0)" ::: "memory");
        __builtin_amdgcn_sched_barrier(0);

        // 3) K-slice dot: per-lane wlds b128 + broadcast hbuf reads + 512 FMA.
        const float4* hb0 = (const float4*)&hbuf[0][w * 128];
        const float4* hb1 = (const float4*)&hbuf[1][w * 128];
        const float4* hb2 = (const float4*)&hbuf[2][w * 128];
        const float4* hb3 = (const float4*)&hbuf[3][w * 128];

        float a0 = 0.f, a1 = 0.f, a2 = 0.f, a3 = 0.f;
        #pragma unroll
        for (int j = 0; j < 32; ++j) {
            const float4 wv = wlds[k4b + j][lane];
            const float4 h0 = hb0[j];
            const float4 h1 = hb1[j];
            const float4 h2 = hb2[j];
            const float4 h3 = hb3[j];
            a0 += wv.x*h0.x; a0 += wv.y*h0.y; a0 += wv.z*h0.z; a0 += wv.w*h0.w;
            a1 += wv.x*h1.x; a1 += wv.y*h1.y; a1 += wv.z*h1.z; a1 += wv.w*h1.w;
            a2 += wv.x*h2.x; a2 += wv.y*h2.y; a2 += wv.z*h2.z; a2 += wv.w*h2.w;
            a3 += wv.x*h3.x; a3 += wv.y*h3.y; a3 += wv.z*h3.z; a3 += wv.w*h3.w;
        }

        // 4) Cross-wave reduce through parity-double-buffered red[].
        const int par = gt & 1;
        red[par][w][0][lane] = a0; red[par][w][1][lane] = a1;
        red[par][w][2][lane] = a2; red[par][w][3][lane] = a3;
        __syncthreads();                         // the ONE block barrier/step

        // Arrival: this block has consumed h(gt-1). 1 add/block/step.
        if (tid == 0)
            __hip_atomic_fetch_add(myctr, 1u, __ATOMIC_RELAXED, __HIP_MEMORY_SCOPE_SYSTEM);

        float g = red[par][0][w][lane] + red[par][1][w][lane]
                + red[par][2][w][lane] + red[par][3][w][lane] + xg;

        const int ul = lane & 15;
        const float fv = __shfl(g, ul);
        const float iv = __shfl(g, ul + 16);
        const float ov = __shfl(g, ul + 32);
        const float gv = __shfl(g, ul + 48);

        // 5) WAR flow control: before overwriting slot[gt&1] (= h(gt-2)),
        // wait until all 32 blocks ended step gt-1 (ctr >= 32*gt). This is
        // ~one full step behind us -> normally passes instantly.
        if (gt >= 2) {
            const unsigned int need = 32u * (unsigned int)gt;
            while (__hip_atomic_load(myctr, __ATOMIC_RELAXED, __HIP_MEMORY_SCOPE_SYSTEM) < need) {}
        }
        asm volatile("" ::: "memory");

        if (lane < 16) {
            const float sf = 1.f / (1.f + __expf(-fv));
            const float si = 1.f / (1.f + __expf(-iv));
            const float so = 1.f / (1.f + __expf(-ov));
            const float tg = 1.f - 2.f / (__expf(2.f * gv) + 1.f);
            c = sf * c + si * tg;
            const float tc = 1.f - 2.f / (__expf(2.f * c) + 1.f);
            const float h = so * tc;
            // Tagged publish: value+tag in one 8B relaxed system-scope store.
            const unsigned long long pk =
                ((unsigned long long)(unsigned int)(gt + 1) << 32) |
                (unsigned long long)__float_as_uint(h);
            __hip_atomic_store(
                hx + (size_t)(gt & 1) * (BB * HH) + (size_t)(4 * p + w) * HH + q * 16 + lane,
                pk, __ATOMIC_RELAXED, __HIP_MEMORY_SCOPE_SYSTEM);
            // Output store: not read in-kernel, off the sync path entirely.
            out[((size_t)(4 * p + w) * TT + gt) * HH + q * 16 + lane] = h;
        }

        xg = xg_next;
    }

    // Spill c state for the next chunk (kernel boundary = coherence).
    if (lane < 16)
        c_ws[(size_t)(4 * p + w) * HH + q * 16 + lane] = c;
}

// ---------------------------------------------------------------------------
extern "C" void kernel_launch(void* const* d_in, const int* in_sizes, int n_in,
                              void* d_out, int out_size, void* d_ws, size_t ws_size,
                              hipStream_t stream) {
    const float* x      = (const float*)d_in[0];
    // d_in[1] = input_paddings (unused)
    const float* W      = (const float*)d_in[2];
    const float* bias   = (const float*)d_in[3];
    const float* h_init = (const float*)d_in[4];
    float* out = (float*)d_out;

    // ws layout: xw (CT*32*2048*4 B) | ctr (2 KB) | c_ws (64 KB) | hx (256 KB)
    static const int cand[] = {2048, 1024, 512, 256, 128, 64, 32, 16, 8, 4};
    const size_t extra = 2048 + 65536 + 262144;
    int CT = 4;
    for (int i = 0; i < 10; ++i) {
        if ((size_t)cand[i] * BB * G4H * 4 + extra <= ws_size) { CT = cand[i]; break; }
    }
    const size_t xw_bytes = (size_t)CT * BB * G4H * 4;
    float*              xw   = (float*)d_ws;
    unsigned int*       ctr  = (unsigned int*)((char*)d_ws + xw_bytes);
    float*              c_ws = (float*)((char*)d_ws + xw_bytes + 2048);
    unsigned long long* hx   = (unsigned long long*)((char*)d_ws + xw_bytes + 2048 + 65536);

    for (int t0 = 0; t0 < TT; t0 += CT) {
        dim3 g(G4H / 128, CT * BB / 128);
        gemm_xw<<<g, 256, 0, stream>>>(x, W, bias, xw, t0, ctr, hx);
        lstm_rec<<<256, 256, 0, stream>>>(W, h_init, xw, out, c_ws, ctr, hx, t0, CT);
    }
}

// Round 11
// 11293.099 us; speedup vs baseline: 1.3452x; 1.0745x over previous
//
#include <hip/hip_runtime.h>
#include <math.h>

// Problem constants (reference: B,T,D,H = 32,2048,512,512)
#define BB   32
#define TT   2048
#define DD   512
#define HH   512
#define G4H  2048   // 4*H

// ---------------------------------------------------------------------------
// Phase A: xw[t_local*32 + b][col] = sum_d X[b][t0+t][d] * W[d][col] + bias[col]
// fp32 tiled GEMM: 128x128 block tile, 16 K-step, 256 threads, 8x8 microtile.
// At t0==0 also zeroes the 8 group counters and the hx tag-exchange buffer
// (tags stored are >=1, so zeroed/poisoned/leftover words can never be
// accepted by a consumer before the real producer writes them).
// ---------------------------------------------------------------------------
__global__ __launch_bounds__(256, 2) void gemm_xw(
    const float* __restrict__ X, const float* __restrict__ Wm,
    const float* __restrict__ bias, float* __restrict__ xw,
    int t0, unsigned int* __restrict__ ctr, unsigned long long* __restrict__ hx)
{
    if (t0 == 0) {
        if (blockIdx.x == 0 && blockIdx.y == 0 && threadIdx.x < 8)
            ctr[threadIdx.x * 64] = 0u;
        if (blockIdx.x == 0) {
            const int n = 2 * BB * HH;               // 32768 u64 slots
            const int stride = gridDim.y * 256;
            for (int i = blockIdx.y * 256 + threadIdx.x; i < n; i += stride)
                hx[i] = 0ull;
        }
    }

    __shared__ float As[16][128];
    __shared__ float Bs[16][128];

    const int tid  = threadIdx.x;
    const int row0 = blockIdx.y * 128;   // rows: (t_local, b) t-major
    const int col0 = blockIdx.x * 128;
    const int tx = tid & 15;
    const int ty = tid >> 4;

    float acc[8][8];
    #pragma unroll
    for (int i = 0; i < 8; ++i)
        #pragma unroll
        for (int j = 0; j < 8; ++j) acc[i][j] = 0.f;

    for (int k0 = 0; k0 < DD; k0 += 16) {
        #pragma unroll
        for (int i = 0; i < 2; ++i) {
            int qa = tid + i * 256;          // 0..511 quads
            int r  = qa >> 2, kq = qa & 3;
            int grow = row0 + r;
            int b = grow & 31, tl = grow >> 5;
            const float4 a = *(const float4*)(X + ((size_t)b * TT + t0 + tl) * DD + k0 + kq * 4);
            As[kq*4+0][r] = a.x; As[kq*4+1][r] = a.y;
            As[kq*4+2][r] = a.z; As[kq*4+3][r] = a.w;

            int qb = tid + i * 256;
            int kb = qb >> 5, c4 = qb & 31;
            *(float4*)&Bs[kb][c4*4] =
                *(const float4*)(Wm + (size_t)(k0 + kb) * G4H + col0 + c4 * 4);
        }
        __syncthreads();

        #pragma unroll
        for (int k = 0; k < 16; ++k) {
            float a[8], b[8];
            #pragma unroll
            for (int i = 0; i < 8; ++i) a[i] = As[k][ty*8 + i];
            #pragma unroll
            for (int j = 0; j < 8; ++j) b[j] = Bs[k][tx*8 + j];
            #pragma unroll
            for (int i = 0; i < 8; ++i)
                #pragma unroll
                for (int j = 0; j < 8; ++j) acc[i][j] += a[i] * b[j];
        }
        __syncthreads();
    }

    #pragma unroll
    for (int i = 0; i < 8; ++i) {
        int grow = row0 + ty*8 + i;
        float* dst = xw + (size_t)grow * G4H + col0 + tx*8;
        #pragma unroll
        for (int j = 0; j < 8; j += 4) {
            float4 v;
            v.x = acc[i][j+0] + bias[col0 + tx*8 + j + 0];
            v.y = acc[i][j+1] + bias[col0 + tx*8 + j + 1];
            v.z = acc[i][j+2] + bias[col0 + tx*8 + j + 2];
            v.w = acc[i][j+3] + bias[col0 + tx*8 + j + 3];
            *(float4*)(dst + j) = v;
        }
    }
}

// ---------------------------------------------------------------------------
// Phase B: persistent recurrent kernel — 8 WAVES (512 threads), tagged
// dataflow h-exchange (R10 protocol), LDS-resident weights.
//
// Grid = 256 blocks. p = blockIdx%8 (batches 4p..4p+3), q = blockIdx/8
// (units 16q..16q+15 -> 64 gate columns, col_local = lane).
// Wave w (0..7) = K-slice of 64. Waves 0-3 also own batch w for the
// reduce/update/publish phase; waves 4-7 skip that phase.
// 8 waves = 2/SIMD: latency hiding that the 4-wave version lacked, and the
// per-lane serial dot chain halves (256 FMA). Ingest narrows to 4 tagged
// words/lane (one per batch). LDS: 128K wlds + 8K hbuf + 16K red = 152 KB.
// Protocol correctness identical to R10 (arrival after barrier => after
// consumption; cumulative ctr WAR check; parity-double-buffered hx/red).
// ---------------------------------------------------------------------------
__global__ __launch_bounds__(512, 1) void lstm_rec(
    const float* __restrict__ W,
    const float* __restrict__ h_init,
    const float* __restrict__ xw,
    float* __restrict__ out,
    float* __restrict__ c_ws,
    unsigned int* ctr,
    unsigned long long* hx,
    int t0, int nT)
{
    __shared__ float4 wlds[128][64];    // [k>>2][col_local] = w[4k..4k+3][col]
    __shared__ float  hbuf[4][HH];      // h staging; region [b][w*64..] is wave-local
    __shared__ float  red[2][8][4][64]; // [parity][kslice-wave][batch][lane]

    const int tid  = threadIdx.x;
    const int p    = blockIdx.x & 7;
    const int q    = blockIdx.x >> 3;
    const int w    = tid >> 6;          // wave id = K-slice; w<4 also = batch owner
    const int lane = tid & 63;
    const int gi   = lane >> 4;
    const int u    = lane & 15;
    const int col  = gi * HH + q * 16 + u;   // this lane's global gate column

    // One-time: stage this block's recurrent W slice into LDS, k-packed.
    // Thread (cc = tid&63, kq = tid>>6 in [0,8)) fills wlds[i*8+kq][cc].
    {
        const int cc = tid & 63;
        const int kq = tid >> 6;
        const int cg = (cc >> 4) * HH + q * 16 + (cc & 15);  // global col of cc
        const float* Wr = W + (size_t)DD * G4H + cg;
        #pragma unroll 4
        for (int i = 0; i < 16; ++i) {
            const int k4 = i * 8 + kq;          // 0..127
            float4 v;
            v.x = Wr[(size_t)(4 * k4 + 0) * G4H];
            v.y = Wr[(size_t)(4 * k4 + 1) * G4H];
            v.z = Wr[(size_t)(4 * k4 + 2) * G4H];
            v.w = Wr[(size_t)(4 * k4 + 3) * G4H];
            wlds[k4][cc] = v;
        }
    }
    __syncthreads();

    // c state: lanes 0..15 of waves 0-3 hold c[batch 4p+w][unit q*16+lane]
    float c = 0.f;
    if (t0 > 0 && w < 4 && lane < 16)
        c = c_ws[(size_t)(4 * p + w) * HH + q * 16 + lane];

    unsigned int* myctr = ctr + p * 64;
    const int hoff = w * 64 + lane;       // this lane's h element (k-slice)

    // Prologue: load xw for step 0 (batch-owner waves only).
    float xg = 0.f;
    if (w < 4)
        xg = xw[((size_t)0 * BB + 4 * p + w) * G4H + col];

    for (int t = 0; t < nT; ++t) {
        const int gt = t0 + t;

        // Prefetch next step's x-part (independent; issues first).
        float xg_next = 0.f;
        if (w < 4 && t + 1 < nT)
            xg_next = xw[((size_t)(t + 1) * BB + 4 * p + w) * G4H + col];

        // 1) h ingest via tagged dataflow: 4 words/lane (one per batch).
        float h0v, h1v, h2v, h3v;
        if (gt == 0) {
            const float hv = h_init[hoff];
            h0v = hv; h1v = hv; h2v = hv; h3v = hv;
        } else {
            const unsigned int want = (unsigned int)gt;   // tag of h(gt-1)
            const unsigned long long* hs = hx + (size_t)((gt - 1) & 1) * (BB * HH);
            const unsigned long long* a0 = hs + (size_t)(4 * p + 0) * HH + hoff;
            const unsigned long long* a1 = hs + (size_t)(4 * p + 1) * HH + hoff;
            const unsigned long long* a2 = hs + (size_t)(4 * p + 2) * HH + hoff;
            const unsigned long long* a3 = hs + (size_t)(4 * p + 3) * HH + hoff;
            unsigned long long v0 = __hip_atomic_load(a0, __ATOMIC_RELAXED, __HIP_MEMORY_SCOPE_SYSTEM);
            unsigned long long v1 = __hip_atomic_load(a1, __ATOMIC_RELAXED, __HIP_MEMORY_SCOPE_SYSTEM);
            unsigned long long v2 = __hip_atomic_load(a2, __ATOMIC_RELAXED, __HIP_MEMORY_SCOPE_SYSTEM);
            unsigned long long v3 = __hip_atomic_load(a3, __ATOMIC_RELAXED, __HIP_MEMORY_SCOPE_SYSTEM);
            for (;;) {
                bool bad = false;
                if ((unsigned int)(v0 >> 32) != want) { bad = true; v0 = __hip_atomic_load(a0, __ATOMIC_RELAXED, __HIP_MEMORY_SCOPE_SYSTEM); }
                if ((unsigned int)(v1 >> 32) != want) { bad = true; v1 = __hip_atomic_load(a1, __ATOMIC_RELAXED, __HIP_MEMORY_SCOPE_SYSTEM); }
                if ((unsigned int)(v2 >> 32) != want) { bad = true; v2 = __hip_atomic_load(a2, __ATOMIC_RELAXED, __HIP_MEMORY_SCOPE_SYSTEM); }
                if ((unsigned int)(v3 >> 32) != want) { bad = true; v3 = __hip_atomic_load(a3, __ATOMIC_RELAXED, __HIP_MEMORY_SCOPE_SYSTEM); }
                if (!bad) break;
            }
            h0v = __uint_as_float((unsigned int)v0);
            h1v = __uint_as_float((unsigned int)v1);
            h2v = __uint_as_float((unsigned int)v2);
            h3v = __uint_as_float((unsigned int)v3);
        }

        // 2) Wave-local stage to LDS (only wave w touches region [*][w*64..]).
        hbuf[0][hoff] = h0v;
        hbuf[1][hoff] = h1v;
        hbuf[2][hoff] = h2v;
        hbuf[3][hoff] = h3v;
        asm volatile("s_waitcnt lgkmcnt(0)" ::: "memory");
        __builtin_amdgcn_sched_barrier(0);

        // 3) K-slice dot: 16 per-lane wlds b128 + broadcast hbuf reads,
        //    256 FMA per lane (half the 4-wave chain).
        const float4* hb0 = (const float4*)&hbuf[0][w * 64];
        const float4* hb1 = (const float4*)&hbuf[1][w * 64];
        const float4* hb2 = (const float4*)&hbuf[2][w * 64];
        const float4* hb3 = (const float4*)&hbuf[3][w * 64];

        float a0 = 0.f, a1 = 0.f, a2 = 0.f, a3 = 0.f;
        #pragma unroll
        for (int j = 0; j < 16; ++j) {
            const float4 wv = wlds[w * 16 + j][lane];
            const float4 h0 = hb0[j];
            const float4 h1 = hb1[j];
            const float4 h2 = hb2[j];
            const float4 h3 = hb3[j];
            a0 += wv.x*h0.x; a0 += wv.y*h0.y; a0 += wv.z*h0.z; a0 += wv.w*h0.w;
            a1 += wv.x*h1.x; a1 += wv.y*h1.y; a1 += wv.z*h1.z; a1 += wv.w*h1.w;
            a2 += wv.x*h2.x; a2 += wv.y*h2.y; a2 += wv.z*h2.z; a2 += wv.w*h2.w;
            a3 += wv.x*h3.x; a3 += wv.y*h3.y; a3 += wv.z*h3.z; a3 += wv.w*h3.w;
        }

        // 4) Cross-wave reduce through parity-double-buffered red[].
        const int par = gt & 1;
        red[par][w][0][lane] = a0; red[par][w][1][lane] = a1;
        red[par][w][2][lane] = a2; red[par][w][3][lane] = a3;
        __syncthreads();                         // the ONE block barrier/step

        // Arrival: this block has consumed h(gt-1). 1 add/block/step.
        if (tid == 0)
            __hip_atomic_fetch_add(myctr, 1u, __ATOMIC_RELAXED, __HIP_MEMORY_SCOPE_SYSTEM);

        if (w < 4) {
            float g = xg;
            #pragma unroll
            for (int s = 0; s < 8; ++s) g += red[par][s][w][lane];

            const int ul = lane & 15;
            const float fv = __shfl(g, ul);
            const float iv = __shfl(g, ul + 16);
            const float ov = __shfl(g, ul + 32);
            const float gv = __shfl(g, ul + 48);

            // WAR flow control: before overwriting slot[gt&1] (= h(gt-2)),
            // wait until all 32 blocks ended step gt-1 (ctr >= 32*gt).
            // Normally already true (arrival precedes publish by a step).
            if (gt >= 2) {
                const unsigned int need = 32u * (unsigned int)gt;
                while (__hip_atomic_load(myctr, __ATOMIC_RELAXED, __HIP_MEMORY_SCOPE_SYSTEM) < need) {}
            }
            asm volatile("" ::: "memory");

            if (lane < 16) {
                const float sf = 1.f / (1.f + __expf(-fv));
                const float si = 1.f / (1.f + __expf(-iv));
                const float so = 1.f / (1.f + __expf(-ov));
                const float tg = 1.f - 2.f / (__expf(2.f * gv) + 1.f);
                c = sf * c + si * tg;
                const float tc = 1.f - 2.f / (__expf(2.f * c) + 1.f);
                const float h = so * tc;
                // Tagged publish: value+tag in one 8B relaxed system store.
                const unsigned long long pk =
                    ((unsigned long long)(unsigned int)(gt + 1) << 32) |
                    (unsigned long long)__float_as_uint(h);
                __hip_atomic_store(
                    hx + (size_t)(gt & 1) * (BB * HH) + (size_t)(4 * p + w) * HH + q * 16 + lane,
                    pk, __ATOMIC_RELAXED, __HIP_MEMORY_SCOPE_SYSTEM);
                // Output store: not read in-kernel, off the sync path.
                out[((size_t)(4 * p + w) * TT + gt) * HH + q * 16 + lane] = h;
            }
        }

        xg = xg_next;
    }

    // Spill c state for the next chunk (kernel boundary = coherence).
    if (w < 4 && lane < 16)
        c_ws[(size_t)(4 * p + w) * HH + q * 16 + lane] = c;
}

// ---------------------------------------------------------------------------
extern "C" void kernel_launch(void* const* d_in, const int* in_sizes, int n_in,
                              void* d_out, int out_size, void* d_ws, size_t ws_size,
                              hipStream_t stream) {
    const float* x      = (const float*)d_in[0];
    // d_in[1] = input_paddings (unused)
    const float* W      = (const float*)d_in[2];
    const float* bias   = (const float*)d_in[3];
    const float* h_init = (const float*)d_in[4];
    float* out = (float*)d_out;

    // ws layout: xw (CT*32*2048*4 B) | ctr (2 KB) | c_ws (64 KB) | hx (256 KB)
    static const int cand[] = {2048, 1024, 512, 256, 128, 64, 32, 16, 8, 4};
    const size_t extra = 2048 + 65536 + 262144;
    int CT = 4;
    for (int i = 0; i < 10; ++i) {
        if ((size_t)cand[i] * BB * G4H * 4 + extra <= ws_size) { CT = cand[i]; break; }
    }
    const size_t xw_bytes = (size_t)CT * BB * G4H * 4;
    float*              xw   = (float*)d_ws;
    unsigned int*       ctr  = (unsigned int*)((char*)d_ws + xw_bytes);
    float*              c_ws = (float*)((char*)d_ws + xw_bytes + 2048);
    unsigned long long* hx   = (unsigned long long*)((char*)d_ws + xw_bytes + 2048 + 65536);

    for (int t0 = 0; t0 < TT; t0 += CT) {
        dim3 g(G4H / 128, CT * BB / 128);
        gemm_xw<<<g, 256, 0, stream>>>(x, W, bias, xw, t0, ctr, hx);
        lstm_rec<<<256, 512, 0, stream>>>(W, h_init, xw, out, c_ws, ctr, hx, t0, CT);
    }
}

// Round 15
// 8790.627 us; speedup vs baseline: 1.7281x; 1.2847x over previous
//
#include <hip/hip_runtime.h>
#include <math.h>

// Problem constants (reference: B,T,D,H = 32,2048,512,512)
#define BB   32
#define TT   2048
#define DD   512
#define HH   512
#define G4H  2048   // 4*H

// ---------------------------------------------------------------------------
// Phase A: xw[t_local*32 + b][col] = sum_d X[b][t0+t][d] * W[d][col] + bias[col]
// fp32 tiled GEMM: 128x128 block tile, 16 K-step, 256 threads, 8x8 microtile.
// At t0==0 also zeroes the 8 group counters and the hx tag-exchange buffer
// (tags stored are >=1, so zeroed/poisoned/leftover words can never be
// accepted by a consumer before the real producer writes them).
// ---------------------------------------------------------------------------
__global__ __launch_bounds__(256, 2) void gemm_xw(
    const float* __restrict__ X, const float* __restrict__ Wm,
    const float* __restrict__ bias, float* __restrict__ xw,
    int t0, unsigned int* __restrict__ ctr, unsigned long long* __restrict__ hx)
{
    if (t0 == 0) {
        if (blockIdx.x == 0 && blockIdx.y == 0 && threadIdx.x < 8)
            ctr[threadIdx.x * 64] = 0u;
        if (blockIdx.x == 0) {
            const int n = 2 * BB * HH;               // 32768 u64 slots
            const int stride = gridDim.y * 256;
            for (int i = blockIdx.y * 256 + threadIdx.x; i < n; i += stride)
                hx[i] = 0ull;
        }
    }

    __shared__ float As[16][128];
    __shared__ float Bs[16][128];

    const int tid  = threadIdx.x;
    const int row0 = blockIdx.y * 128;   // rows: (t_local, b) t-major
    const int col0 = blockIdx.x * 128;
    const int tx = tid & 15;
    const int ty = tid >> 4;

    float acc[8][8];
    #pragma unroll
    for (int i = 0; i < 8; ++i)
        #pragma unroll
        for (int j = 0; j < 8; ++j) acc[i][j] = 0.f;

    for (int k0 = 0; k0 < DD; k0 += 16) {
        #pragma unroll
        for (int i = 0; i < 2; ++i) {
            int qa = tid + i * 256;          // 0..511 quads
            int r  = qa >> 2, kq = qa & 3;
            int grow = row0 + r;
            int b = grow & 31, tl = grow >> 5;
            const float4 a = *(const float4*)(X + ((size_t)b * TT + t0 + tl) * DD + k0 + kq * 4);
            As[kq*4+0][r] = a.x; As[kq*4+1][r] = a.y;
            As[kq*4+2][r] = a.z; As[kq*4+3][r] = a.w;

            int qb = tid + i * 256;
            int kb = qb >> 5, c4 = qb & 31;
            *(float4*)&Bs[kb][c4*4] =
                *(const float4*)(Wm + (size_t)(k0 + kb) * G4H + col0 + c4 * 4);
        }
        __syncthreads();

        #pragma unroll
        for (int k = 0; k < 16; ++k) {
            float a[8], b[8];
            #pragma unroll
            for (int i = 0; i < 8; ++i) a[i] = As[k][ty*8 + i];
            #pragma unroll
            for (int j = 0; j < 8; ++j) b[j] = Bs[k][tx*8 + j];
            #pragma unroll
            for (int i = 0; i < 8; ++i)
                #pragma unroll
                for (int j = 0; j < 8; ++j) acc[i][j] += a[i] * b[j];
        }
        __syncthreads();
    }

    #pragma unroll
    for (int i = 0; i < 8; ++i) {
        int grow = row0 + ty*8 + i;
        float* dst = xw + (size_t)grow * G4H + col0 + tx*8;
        #pragma unroll
        for (int j = 0; j < 8; j += 4) {
            float4 v;
            v.x = acc[i][j+0] + bias[col0 + tx*8 + j + 0];
            v.y = acc[i][j+1] + bias[col0 + tx*8 + j + 1];
            v.z = acc[i][j+2] + bias[col0 + tx*8 + j + 2];
            v.w = acc[i][j+3] + bias[col0 + tx*8 + j + 3];
            *(float4*)(dst + j) = v;
        }
    }
}

// ---------------------------------------------------------------------------
// Phase B: 8-wave (512-thread) persistent recurrent kernel, tagged-dataflow
// h exchange — the R11 kernel (known good) plus two protocol-neutral fixes:
//   (a) WAR counter sampled early (non-blocking, right after h ingest),
//       re-checked after the reduce — off the publish critical path;
//   (b) s_sleep(1) in the rarely-taken WAR retry loop.
// ALL cross-block traffic is system-scope (L3 point) — the only scope whose
// progress is verifiable on this platform (XCD-locality experiment closed
// after two R13/R14 deadlocks: sc0 lines can hide in a non-shared L2).
//
// Grid = 256 blocks. p = blockIdx%8 (batches 4p..4p+3), q = blockIdx/8
// (units 16q..16q+15 -> 64 gate columns, col_local = lane).
// Wave w (0..7) = K-slice of 64. Waves 0-3 also own batch w for the
// reduce/update/publish phase; waves 4-7 skip that phase.
// h element = one 8B word {tag = step+1 (hi32), fp32 h bits (lo32)} in
// hx[2][32][512], parity-double-buffered; consumers spin on the tags of
// exactly the 4 words/lane they need. WAR protection: before overwriting
// slot[gt&1] (= h(gt-2)), require ctr >= 32*gt (all blocks ended step gt-1).
// Arrival = 1 fetch_add per block per step, after the reduce barrier.
// ---------------------------------------------------------------------------
__global__ __launch_bounds__(512, 1) void lstm_rec(
    const float* __restrict__ W,
    const float* __restrict__ h_init,
    const float* __restrict__ xw,
    float* __restrict__ out,
    float* __restrict__ c_ws,
    unsigned int* ctr,
    unsigned long long* hx,
    int t0, int nT)
{
    __shared__ float4 wlds[128][64];    // [k>>2][col_local] = w[4k..4k+3][col]
    __shared__ float  hbuf[4][HH];      // h staging; region [b][w*64..] is wave-local
    __shared__ float  red[2][8][4][64]; // [parity][kslice-wave][batch][lane]

    const int tid  = threadIdx.x;
    const int p    = blockIdx.x & 7;
    const int q    = blockIdx.x >> 3;
    const int w    = tid >> 6;          // wave id = K-slice; w<4 also = batch owner
    const int lane = tid & 63;
    const int gi   = lane >> 4;
    const int u    = lane & 15;
    const int col  = gi * HH + q * 16 + u;   // this lane's global gate column

    // One-time: stage this block's recurrent W slice into LDS, k-packed.
    {
        const int cc = tid & 63;
        const int kq = tid >> 6;
        const int cg = (cc >> 4) * HH + q * 16 + (cc & 15);  // global col of cc
        const float* Wr = W + (size_t)DD * G4H + cg;
        #pragma unroll 4
        for (int i = 0; i < 16; ++i) {
            const int k4 = i * 8 + kq;          // 0..127
            float4 v;
            v.x = Wr[(size_t)(4 * k4 + 0) * G4H];
            v.y = Wr[(size_t)(4 * k4 + 1) * G4H];
            v.z = Wr[(size_t)(4 * k4 + 2) * G4H];
            v.w = Wr[(size_t)(4 * k4 + 3) * G4H];
            wlds[k4][cc] = v;
        }
    }
    __syncthreads();

    // c state: lanes 0..15 of waves 0-3 hold c[batch 4p+w][unit q*16+lane]
    float c = 0.f;
    if (t0 > 0 && w < 4 && lane < 16)
        c = c_ws[(size_t)(4 * p + w) * HH + q * 16 + lane];

    unsigned int* myctr = ctr + p * 64;
    const int hoff = w * 64 + lane;       // this lane's h element (k-slice)

    // Prologue: load xw for step 0 (batch-owner waves only).
    float xg = 0.f;
    if (w < 4)
        xg = xw[((size_t)0 * BB + 4 * p + w) * G4H + col];

    for (int t = 0; t < nT; ++t) {
        const int gt = t0 + t;

        // Prefetch next step's x-part (independent; issues first).
        float xg_next = 0.f;
        if (w < 4 && t + 1 < nT)
            xg_next = xw[((size_t)(t + 1) * BB + 4 * p + w) * G4H + col];

        // 1) h ingest via tagged dataflow: 4 words/lane (one per batch).
        float h0v, h1v, h2v, h3v;
        if (gt == 0) {
            const float hv = h_init[hoff];
            h0v = hv; h1v = hv; h2v = hv; h3v = hv;
        } else {
            const unsigned int want = (unsigned int)gt;   // tag of h(gt-1)
            const unsigned long long* hs = hx + (size_t)((gt - 1) & 1) * (BB * HH);
            const unsigned long long* a0 = hs + (size_t)(4 * p + 0) * HH + hoff;
            const unsigned long long* a1 = hs + (size_t)(4 * p + 1) * HH + hoff;
            const unsigned long long* a2 = hs + (size_t)(4 * p + 2) * HH + hoff;
            const unsigned long long* a3 = hs + (size_t)(4 * p + 3) * HH + hoff;
            unsigned long long v0 = __hip_atomic_load(a0, __ATOMIC_RELAXED, __HIP_MEMORY_SCOPE_SYSTEM);
            unsigned long long v1 = __hip_atomic_load(a1, __ATOMIC_RELAXED, __HIP_MEMORY_SCOPE_SYSTEM);
            unsigned long long v2 = __hip_atomic_load(a2, __ATOMIC_RELAXED, __HIP_MEMORY_SCOPE_SYSTEM);
            unsigned long long v3 = __hip_atomic_load(a3, __ATOMIC_RELAXED, __HIP_MEMORY_SCOPE_SYSTEM);
            for (;;) {
                bool bad = false;
                if ((unsigned int)(v0 >> 32) != want) { bad = true; v0 = __hip_atomic_load(a0, __ATOMIC_RELAXED, __HIP_MEMORY_SCOPE_SYSTEM); }
                if ((unsigned int)(v1 >> 32) != want) { bad = true; v1 = __hip_atomic_load(a1, __ATOMIC_RELAXED, __HIP_MEMORY_SCOPE_SYSTEM); }
                if ((unsigned int)(v2 >> 32) != want) { bad = true; v2 = __hip_atomic_load(a2, __ATOMIC_RELAXED, __HIP_MEMORY_SCOPE_SYSTEM); }
                if ((unsigned int)(v3 >> 32) != want) { bad = true; v3 = __hip_atomic_load(a3, __ATOMIC_RELAXED, __HIP_MEMORY_SCOPE_SYSTEM); }
                if (!bad) break;
            }
            h0v = __uint_as_float((unsigned int)v0);
            h1v = __uint_as_float((unsigned int)v1);
            h2v = __uint_as_float((unsigned int)v2);
            h3v = __uint_as_float((unsigned int)v3);
        }

        // WAR counter: non-blocking early sample (re-checked after reduce).
        unsigned warv = 0;
        if (w < 4 && gt >= 2)
            warv = __hip_atomic_load(myctr, __ATOMIC_RELAXED, __HIP_MEMORY_SCOPE_SYSTEM);

        // 2) Wave-local stage to LDS (only wave w touches region [*][w*64..]).
        hbuf[0][hoff] = h0v;
        hbuf[1][hoff] = h1v;
        hbuf[2][hoff] = h2v;
        hbuf[3][hoff] = h3v;
        asm volatile("s_waitcnt lgkmcnt(0)" ::: "memory");
        __builtin_amdgcn_sched_barrier(0);

        // 3) K-slice dot: 16 per-lane wlds b128 + broadcast hbuf reads,
        //    256 FMA per lane.
        const float4* hb0 = (const float4*)&hbuf[0][w * 64];
        const float4* hb1 = (const float4*)&hbuf[1][w * 64];
        const float4* hb2 = (const float4*)&hbuf[2][w * 64];
        const float4* hb3 = (const float4*)&hbuf[3][w * 64];

        float a0 = 0.f, a1 = 0.f, a2 = 0.f, a3 = 0.f;
        #pragma unroll
        for (int j = 0; j < 16; ++j) {
            const float4 wv = wlds[w * 16 + j][lane];
            const float4 h0 = hb0[j];
            const float4 h1 = hb1[j];
            const float4 h2 = hb2[j];
            const float4 h3 = hb3[j];
            a0 += wv.x*h0.x; a0 += wv.y*h0.y; a0 += wv.z*h0.z; a0 += wv.w*h0.w;
            a1 += wv.x*h1.x; a1 += wv.y*h1.y; a1 += wv.z*h1.z; a1 += wv.w*h1.w;
            a2 += wv.x*h2.x; a2 += wv.y*h2.y; a2 += wv.z*h2.z; a2 += wv.w*h2.w;
            a3 += wv.x*h3.x; a3 += wv.y*h3.y; a3 += wv.z*h3.z; a3 += wv.w*h3.w;
        }

        // 4) Cross-wave reduce through parity-double-buffered red[].
        const int par = gt & 1;
        red[par][w][0][lane] = a0; red[par][w][1][lane] = a1;
        red[par][w][2][lane] = a2; red[par][w][3][lane] = a3;
        __syncthreads();                         // the ONE block barrier/step

        // Arrival: this block has consumed h(gt-1). 1 add/block/step.
        if (tid == 0)
            __hip_atomic_fetch_add(myctr, 1u, __ATOMIC_RELAXED, __HIP_MEMORY_SCOPE_SYSTEM);

        if (w < 4) {
            float g = xg;
            #pragma unroll
            for (int s = 0; s < 8; ++s) g += red[par][s][w][lane];

            const int ul = lane & 15;
            const float fv = __shfl(g, ul);
            const float iv = __shfl(g, ul + 16);
            const float ov = __shfl(g, ul + 32);
            const float gv = __shfl(g, ul + 48);

            // WAR flow control (slot gt&1 holds h(gt-2)): early sample
            // normally satisfies it; retry with s_sleep (rare path).
            if (gt >= 2) {
                const unsigned need = 32u * (unsigned)gt;
                while (warv < need) {
                    __builtin_amdgcn_s_sleep(1);
                    warv = __hip_atomic_load(myctr, __ATOMIC_RELAXED, __HIP_MEMORY_SCOPE_SYSTEM);
                }
            }
            asm volatile("" ::: "memory");

            if (lane < 16) {
                const float sf = 1.f / (1.f + __expf(-fv));
                const float si = 1.f / (1.f + __expf(-iv));
                const float so = 1.f / (1.f + __expf(-ov));
                const float tg = 1.f - 2.f / (__expf(2.f * gv) + 1.f);
                c = sf * c + si * tg;
                const float tc = 1.f - 2.f / (__expf(2.f * c) + 1.f);
                const float h = so * tc;
                // Tagged publish: value+tag in one 8B relaxed system store.
                const unsigned long long pk =
                    ((unsigned long long)(unsigned int)(gt + 1) << 32) |
                    (unsigned long long)__float_as_uint(h);
                __hip_atomic_store(
                    hx + (size_t)(gt & 1) * (BB * HH) + (size_t)(4 * p + w) * HH + q * 16 + lane,
                    pk, __ATOMIC_RELAXED, __HIP_MEMORY_SCOPE_SYSTEM);
                // Output store: not read in-kernel, off the sync path.
                out[((size_t)(4 * p + w) * TT + gt) * HH + q * 16 + lane] = h;
            }
        }

        xg = xg_next;
    }

    // Spill c state for the next chunk (kernel boundary = coherence).
    if (w < 4 && lane < 16)
        c_ws[(size_t)(4 * p + w) * HH + q * 16 + lane] = c;
}

// ---------------------------------------------------------------------------
extern "C" void kernel_launch(void* const* d_in, const int* in_sizes, int n_in,
                              void* d_out, int out_size, void* d_ws, size_t ws_size,
                              hipStream_t stream) {
    const float* x      = (const float*)d_in[0];
    // d_in[1] = input_paddings (unused)
    const float* W      = (const float*)d_in[2];
    const float* bias   = (const float*)d_in[3];
    const float* h_init = (const float*)d_in[4];
    float* out = (float*)d_out;

    // ws layout: xw (CT*32*2048*4 B) | ctr (2 KB) | c_ws (64 KB) | hx (256 KB)
    static const int cand[] = {2048, 1024, 512, 256, 128, 64, 32, 16, 8, 4};
    const size_t extra = 2048 + 65536 + 262144;
    int CT = 4;
    for (int i = 0; i < 10; ++i) {
        if ((size_t)cand[i] * BB * G4H * 4 + extra <= ws_size) { CT = cand[i]; break; }
    }
    const size_t xw_bytes = (size_t)CT * BB * G4H * 4;
    float*              xw   = (float*)d_ws;
    unsigned int*       ctr  = (unsigned int*)((char*)d_ws + xw_bytes);
    float*              c_ws = (float*)((char*)d_ws + xw_bytes + 2048);
    unsigned long long* hx   = (unsigned long long*)((char*)d_ws + xw_bytes + 2048 + 65536);

    for (int t0 = 0; t0 < TT; t0 += CT) {
        dim3 g(G4H / 128, CT * BB / 128);
        gemm_xw<<<g, 256, 0, stream>>>(x, W, bias, xw, t0, ctr, hx);
        lstm_rec<<<256, 512, 0, stream>>>(W, h_init, xw, out, c_ws, ctr, hx, t0, CT);
    }
}

// Round 16
// 8671.925 us; speedup vs baseline: 1.7518x; 1.0137x over previous
//
#include <hip/hip_runtime.h>
#include <math.h>

// Problem constants (reference: B,T,D,H = 32,2048,512,512)
#define BB   32
#define TT   2048
#define DD   512
#define HH   512
#define G4H  2048   // 4*H

// ---------------------------------------------------------------------------
// Phase A: xw[t_local*32 + b][col] = sum_d X[b][t0+t][d] * W[d][col] + bias[col]
// fp32 tiled GEMM: 128x128 block tile, 16 K-step, 256 threads, 8x8 microtile.
// At t0==0 also zeroes the 8 group counters and the hx tag-exchange buffer.
// ---------------------------------------------------------------------------
__global__ __launch_bounds__(256, 2) void gemm_xw(
    const float* __restrict__ X, const float* __restrict__ Wm,
    const float* __restrict__ bias, float* __restrict__ xw,
    int t0, unsigned int* __restrict__ ctr, unsigned long long* __restrict__ hx)
{
    if (t0 == 0) {
        if (blockIdx.x == 0 && blockIdx.y == 0 && threadIdx.x < 8)
            ctr[threadIdx.x * 64] = 0u;
        if (blockIdx.x == 0) {
            const int n = 2 * BB * HH;               // 32768 u64 slots
            const int stride = gridDim.y * 256;
            for (int i = blockIdx.y * 256 + threadIdx.x; i < n; i += stride)
                hx[i] = 0ull;
        }
    }

    __shared__ float As[16][128];
    __shared__ float Bs[16][128];

    const int tid  = threadIdx.x;
    const int row0 = blockIdx.y * 128;   // rows: (t_local, b) t-major
    const int col0 = blockIdx.x * 128;
    const int tx = tid & 15;
    const int ty = tid >> 4;

    float acc[8][8];
    #pragma unroll
    for (int i = 0; i < 8; ++i)
        #pragma unroll
        for (int j = 0; j < 8; ++j) acc[i][j] = 0.f;

    for (int k0 = 0; k0 < DD; k0 += 16) {
        #pragma unroll
        for (int i = 0; i < 2; ++i) {
            int qa = tid + i * 256;          // 0..511 quads
            int r  = qa >> 2, kq = qa & 3;
            int grow = row0 + r;
            int b = grow & 31, tl = grow >> 5;
            const float4 a = *(const float4*)(X + ((size_t)b * TT + t0 + tl) * DD + k0 + kq * 4);
            As[kq*4+0][r] = a.x; As[kq*4+1][r] = a.y;
            As[kq*4+2][r] = a.z; As[kq*4+3][r] = a.w;

            int qb = tid + i * 256;
            int kb = qb >> 5, c4 = qb & 31;
            *(float4*)&Bs[kb][c4*4] =
                *(const float4*)(Wm + (size_t)(k0 + kb) * G4H + col0 + c4 * 4);
        }
        __syncthreads();

        #pragma unroll
        for (int k = 0; k < 16; ++k) {
            float a[8], b[8];
            #pragma unroll
            for (int i = 0; i < 8; ++i) a[i] = As[k][ty*8 + i];
            #pragma unroll
            for (int j = 0; j < 8; ++j) b[j] = Bs[k][tx*8 + j];
            #pragma unroll
            for (int i = 0; i < 8; ++i)
                #pragma unroll
                for (int j = 0; j < 8; ++j) acc[i][j] += a[i] * b[j];
        }
        __syncthreads();
    }

    #pragma unroll
    for (int i = 0; i < 8; ++i) {
        int grow = row0 + ty*8 + i;
        float* dst = xw + (size_t)grow * G4H + col0 + tx*8;
        #pragma unroll
        for (int j = 0; j < 8; j += 4) {
            float4 v;
            v.x = acc[i][j+0] + bias[col0 + tx*8 + j + 0];
            v.y = acc[i][j+1] + bias[col0 + tx*8 + j + 1];
            v.z = acc[i][j+2] + bias[col0 + tx*8 + j + 2];
            v.w = acc[i][j+3] + bias[col0 + tx*8 + j + 3];
            *(float4*)(dst + j) = v;
        }
    }
}

// ---------------------------------------------------------------------------
// Phase B: 8-wave (512-thread) persistent recurrent kernel, tagged-dataflow
// h exchange — R15 kernel (known good, 3.84 us/step) + two critical-path
// shavings, protocol unchanged:
//   (a) unit-major h staging hb4[512] (float4 = 4 batches): ONE
//       ds_write_b128 per lane instead of 4 scattered b32;
//   (b) parallel gate activations: every lane applies its own
//       sigmoid/tanh BEFORE the shfl gather (was 4 serial transcendentals
//       on 16 lanes after the gather). Arithmetic identical.
// ALL cross-block traffic is system-scope (L3 point) — the only scope with
// verifiable progress on this platform (XCD/sc0 experiment closed, R13/R14).
// ---------------------------------------------------------------------------
__global__ __launch_bounds__(512, 1) void lstm_rec(
    const float* __restrict__ W,
    const float* __restrict__ h_init,
    const float* __restrict__ xw,
    float* __restrict__ out,
    float* __restrict__ c_ws,
    unsigned int* ctr,
    unsigned long long* hx,
    int t0, int nT)
{
    __shared__ float4 wlds[128][64];    // [k>>2][col_local] = w[4k..4k+3][col]
    __shared__ float4 hb4[512];         // [k] = {h_b0,h_b1,h_b2,h_b3}; [w*64..] wave-local
    __shared__ float  red[2][8][4][64]; // [parity][kslice-wave][batch][lane]

    const int tid  = threadIdx.x;
    const int p    = blockIdx.x & 7;
    const int q    = blockIdx.x >> 3;
    const int w    = tid >> 6;          // wave id = K-slice; w<4 also = batch owner
    const int lane = tid & 63;
    const int gi   = lane >> 4;
    const int u    = lane & 15;
    const int col  = gi * HH + q * 16 + u;   // this lane's global gate column

    // One-time: stage this block's recurrent W slice into LDS, k-packed.
    {
        const int cc = tid & 63;
        const int kq = tid >> 6;
        const int cg = (cc >> 4) * HH + q * 16 + (cc & 15);  // global col of cc
        const float* Wr = W + (size_t)DD * G4H + cg;
        #pragma unroll 4
        for (int i = 0; i < 16; ++i) {
            const int k4 = i * 8 + kq;          // 0..127
            float4 v;
            v.x = Wr[(size_t)(4 * k4 + 0) * G4H];
            v.y = Wr[(size_t)(4 * k4 + 1) * G4H];
            v.z = Wr[(size_t)(4 * k4 + 2) * G4H];
            v.w = Wr[(size_t)(4 * k4 + 3) * G4H];
            wlds[k4][cc] = v;
        }
    }
    __syncthreads();

    // c state: lanes 0..15 of waves 0-3 hold c[batch 4p+w][unit q*16+lane]
    float c = 0.f;
    if (t0 > 0 && w < 4 && lane < 16)
        c = c_ws[(size_t)(4 * p + w) * HH + q * 16 + lane];

    unsigned int* myctr = ctr + p * 64;
    const int hoff = w * 64 + lane;       // this lane's h element (k-slice)

    // Prologue: load xw for step 0 (batch-owner waves only).
    float xg = 0.f;
    if (w < 4)
        xg = xw[((size_t)0 * BB + 4 * p + w) * G4H + col];

    for (int t = 0; t < nT; ++t) {
        const int gt = t0 + t;

        // Prefetch next step's x-part (independent; issues first).
        float xg_next = 0.f;
        if (w < 4 && t + 1 < nT)
            xg_next = xw[((size_t)(t + 1) * BB + 4 * p + w) * G4H + col];

        // 1) h ingest via tagged dataflow: 4 words/lane (one per batch).
        float h0v, h1v, h2v, h3v;
        if (gt == 0) {
            const float hv = h_init[hoff];
            h0v = hv; h1v = hv; h2v = hv; h3v = hv;
        } else {
            const unsigned int want = (unsigned int)gt;   // tag of h(gt-1)
            const unsigned long long* hs = hx + (size_t)((gt - 1) & 1) * (BB * HH);
            const unsigned long long* a0 = hs + (size_t)(4 * p + 0) * HH + hoff;
            const unsigned long long* a1 = hs + (size_t)(4 * p + 1) * HH + hoff;
            const unsigned long long* a2 = hs + (size_t)(4 * p + 2) * HH + hoff;
            const unsigned long long* a3 = hs + (size_t)(4 * p + 3) * HH + hoff;
            unsigned long long v0 = __hip_atomic_load(a0, __ATOMIC_RELAXED, __HIP_MEMORY_SCOPE_SYSTEM);
            unsigned long long v1 = __hip_atomic_load(a1, __ATOMIC_RELAXED, __HIP_MEMORY_SCOPE_SYSTEM);
            unsigned long long v2 = __hip_atomic_load(a2, __ATOMIC_RELAXED, __HIP_MEMORY_SCOPE_SYSTEM);
            unsigned long long v3 = __hip_atomic_load(a3, __ATOMIC_RELAXED, __HIP_MEMORY_SCOPE_SYSTEM);
            for (;;) {
                bool bad = false;
                if ((unsigned int)(v0 >> 32) != want) { bad = true; v0 = __hip_atomic_load(a0, __ATOMIC_RELAXED, __HIP_MEMORY_SCOPE_SYSTEM); }
                if ((unsigned int)(v1 >> 32) != want) { bad = true; v1 = __hip_atomic_load(a1, __ATOMIC_RELAXED, __HIP_MEMORY_SCOPE_SYSTEM); }
                if ((unsigned int)(v2 >> 32) != want) { bad = true; v2 = __hip_atomic_load(a2, __ATOMIC_RELAXED, __HIP_MEMORY_SCOPE_SYSTEM); }
                if ((unsigned int)(v3 >> 32) != want) { bad = true; v3 = __hip_atomic_load(a3, __ATOMIC_RELAXED, __HIP_MEMORY_SCOPE_SYSTEM); }
                if (!bad) break;
            }
            h0v = __uint_as_float((unsigned int)v0);
            h1v = __uint_as_float((unsigned int)v1);
            h2v = __uint_as_float((unsigned int)v2);
            h3v = __uint_as_float((unsigned int)v3);
        }

        // WAR counter: non-blocking early sample (re-checked after reduce).
        unsigned warv = 0;
        if (w < 4 && gt >= 2)
            warv = __hip_atomic_load(myctr, __ATOMIC_RELAXED, __HIP_MEMORY_SCOPE_SYSTEM);

        // 2) Wave-local stage: ONE ds_write_b128 (unit-major, 4 batches).
        float4 hv4; hv4.x = h0v; hv4.y = h1v; hv4.z = h2v; hv4.w = h3v;
        hb4[hoff] = hv4;
        asm volatile("s_waitcnt lgkmcnt(0)" ::: "memory");
        __builtin_amdgcn_sched_barrier(0);

        // 3) K-slice dot: 16 per-lane wlds b128 + 4 broadcast b128 per j,
        //    256 FMA per lane. hb4 row r = {h_b0..h_b3} at k=r.
        const int base = w * 16;
        float a0 = 0.f, a1 = 0.f, a2 = 0.f, a3 = 0.f;
        #pragma unroll
        for (int j = 0; j < 16; ++j) {
            const float4 wv = wlds[base + j][lane];
            const float4 r0 = hb4[w * 64 + 4 * j + 0];
            const float4 r1 = hb4[w * 64 + 4 * j + 1];
            const float4 r2 = hb4[w * 64 + 4 * j + 2];
            const float4 r3 = hb4[w * 64 + 4 * j + 3];
            a0 += wv.x*r0.x; a1 += wv.x*r0.y; a2 += wv.x*r0.z; a3 += wv.x*r0.w;
            a0 += wv.y*r1.x; a1 += wv.y*r1.y; a2 += wv.y*r1.z; a3 += wv.y*r1.w;
            a0 += wv.z*r2.x; a1 += wv.z*r2.y; a2 += wv.z*r2.z; a3 += wv.z*r2.w;
            a0 += wv.w*r3.x; a1 += wv.w*r3.y; a2 += wv.w*r3.z; a3 += wv.w*r3.w;
        }

        // 4) Cross-wave reduce through parity-double-buffered red[].
        const int par = gt & 1;
        red[par][w][0][lane] = a0; red[par][w][1][lane] = a1;
        red[par][w][2][lane] = a2; red[par][w][3][lane] = a3;
        __syncthreads();                         // the ONE block barrier/step

        // Arrival: this block has consumed h(gt-1). 1 add/block/step.
        if (tid == 0)
            __hip_atomic_fetch_add(myctr, 1u, __ATOMIC_RELAXED, __HIP_MEMORY_SCOPE_SYSTEM);

        if (w < 4) {
            float g = xg;
            #pragma unroll
            for (int s = 0; s < 8; ++s) g += red[par][s][w][lane];

            // Per-lane activation BEFORE gather: lane's own gate type only.
            // gi 0,1,2 -> sigmoid; gi 3 -> tanh. (Identical arithmetic.)
            float act;
            if (gi == 3) act = 1.f - 2.f / (__expf(2.f * g) + 1.f);
            else         act = 1.f / (1.f + __expf(-g));

            const int ul = lane & 15;
            const float fv = __shfl(act, ul);
            const float iv = __shfl(act, ul + 16);
            const float ov = __shfl(act, ul + 32);
            const float gv = __shfl(act, ul + 48);

            // WAR flow control (slot gt&1 holds h(gt-2)): early sample
            // normally satisfies it; retry with s_sleep (rare path).
            if (gt >= 2) {
                const unsigned need = 32u * (unsigned)gt;
                while (warv < need) {
                    __builtin_amdgcn_s_sleep(1);
                    warv = __hip_atomic_load(myctr, __ATOMIC_RELAXED, __HIP_MEMORY_SCOPE_SYSTEM);
                }
            }
            asm volatile("" ::: "memory");

            if (lane < 16) {
                c = fv * c + iv * gv;
                const float tc = 1.f - 2.f / (__expf(2.f * c) + 1.f);
                const float h = ov * tc;
                // Tagged publish: value+tag in one 8B relaxed system store.
                const unsigned long long pk =
                    ((unsigned long long)(unsigned int)(gt + 1) << 32) |
                    (unsigned long long)__float_as_uint(h);
                __hip_atomic_store(
                    hx + (size_t)(gt & 1) * (BB * HH) + (size_t)(4 * p + w) * HH + q * 16 + lane,
                    pk, __ATOMIC_RELAXED, __HIP_MEMORY_SCOPE_SYSTEM);
                // Output store: not read in-kernel, off the sync path.
                out[((size_t)(4 * p + w) * TT + gt) * HH + q * 16 + lane] = h;
            }
        }

        xg = xg_next;
    }

    // Spill c state for the next chunk (kernel boundary = coherence).
    if (w < 4 && lane < 16)
        c_ws[(size_t)(4 * p + w) * HH + q * 16 + lane] = c;
}

// ---------------------------------------------------------------------------
extern "C" void kernel_launch(void* const* d_in, const int* in_sizes, int n_in,
                              void* d_out, int out_size, void* d_ws, size_t ws_size,
                              hipStream_t stream) {
    const float* x      = (const float*)d_in[0];
    // d_in[1] = input_paddings (unused)
    const float* W      = (const float*)d_in[2];
    const float* bias   = (const float*)d_in[3];
    const float* h_init = (const float*)d_in[4];
    float* out = (float*)d_out;

    // ws layout: xw (CT*32*2048*4 B) | ctr (2 KB) | c_ws (64 KB) | hx (256 KB)
    static const int cand[] = {2048, 1024, 512, 256, 128, 64, 32, 16, 8, 4};
    const size_t extra = 2048 + 65536 + 262144;
    int CT = 4;
    for (int i = 0; i < 10; ++i) {
        if ((size_t)cand[i] * BB * G4H * 4 + extra <= ws_size) { CT = cand[i]; break; }
    }
    const size_t xw_bytes = (size_t)CT * BB * G4H * 4;
    float*              xw   = (float*)d_ws;
    unsigned int*       ctr  = (unsigned int*)((char*)d_ws + xw_bytes);
    float*              c_ws = (float*)((char*)d_ws + xw_bytes + 2048);
    unsigned long long* hx   = (unsigned long long*)((char*)d_ws + xw_bytes + 2048 + 65536);

    for (int t0 = 0; t0 < TT; t0 += CT) {
        dim3 g(G4H / 128, CT * BB / 128);
        gemm_xw<<<g, 256, 0, stream>>>(x, W, bias, xw, t0, ctr, hx);
        lstm_rec<<<256, 512, 0, stream>>>(W, h_init, xw, out, c_ws, ctr, hx, t0, CT);
    }
}